// Round 1
// baseline (1303.488 us; speedup 1.0000x reference)
//
#include <hip/hip_runtime.h>
#include <hip/hip_bf16.h>
#include <math.h>

#define B_ 4
#define S_ 2048
#define D_ 256
#define H_ 8
#define HD_ 32
#define DFF_ 512

// ---------------- generic NT GEMM: C[M,N] = A[M,K] * W[N,K]^T + bias, optional SiLU
template<int ACT>
__global__ __launch_bounds__(256) void gemm_nt(const float* __restrict__ A,
                                               const float* __restrict__ W,
                                               const float* __restrict__ bias,
                                               float* __restrict__ C,
                                               int M, int N, int K) {
  constexpr int BM = 64, BN = 64, BK = 16;
  __shared__ float As[BK][BM];   // k-major, rows 256B -> aligned b128 reads
  __shared__ float Ws[BK][BN];
  const int tid = threadIdx.x;
  const int tx = tid & 15, ty = tid >> 4;
  const int rowBase = blockIdx.y * BM;
  const int colBase = blockIdx.x * BN;
  float acc[4][4] = {};
  for (int k0 = 0; k0 < K; k0 += BK) {
    __syncthreads();
    {
      int r  = tid >> 2;         // 0..63
      int k4 = (tid & 3) * 4;    // 0,4,8,12
      float4 v = *(const float4*)(A + (size_t)(rowBase + r) * K + k0 + k4);
      As[k4 + 0][r] = v.x; As[k4 + 1][r] = v.y; As[k4 + 2][r] = v.z; As[k4 + 3][r] = v.w;
      float4 wv = *(const float4*)(W + (size_t)(colBase + r) * K + k0 + k4);
      Ws[k4 + 0][r] = wv.x; Ws[k4 + 1][r] = wv.y; Ws[k4 + 2][r] = wv.z; Ws[k4 + 3][r] = wv.w;
    }
    __syncthreads();
#pragma unroll
    for (int kk = 0; kk < BK; ++kk) {
      float4 a4 = *(const float4*)&As[kk][ty * 4];
      float4 b4 = *(const float4*)&Ws[kk][tx * 4];
      float av[4] = {a4.x, a4.y, a4.z, a4.w};
      float bv[4] = {b4.x, b4.y, b4.z, b4.w};
#pragma unroll
      for (int i = 0; i < 4; ++i)
#pragma unroll
        for (int j = 0; j < 4; ++j)
          acc[i][j] = fmaf(av[i], bv[j], acc[i][j]);
    }
  }
#pragma unroll
  for (int i = 0; i < 4; ++i) {
    int row = rowBase + ty * 4 + i;
#pragma unroll
    for (int j = 0; j < 4; ++j) {
      int col = colBase + tx * 4 + j;
      float v = acc[i][j] + bias[col];
      if (ACT == 1) v = v / (1.f + __expf(-v));   // SiLU
      C[(size_t)row * N + col] = v;
    }
  }
}

// ---------------- flash-style attention, f32
// grid: (S/QT) * H * B ; block 128 threads, one q-row per thread
__global__ __launch_bounds__(128) void attn_kernel(const float* __restrict__ qkv,
                                                   const float* __restrict__ cutoff,
                                                   float* __restrict__ out) {
  constexpr int QT = 128, KT = 64;
  const int nqt = S_ / QT;
  const int qt = blockIdx.x % nqt;
  const int h  = (blockIdx.x / nqt) % H_;
  const int b  = blockIdx.x / (nqt * H_);
  const int t  = threadIdx.x;
  const int qr = qt * QT + t;

  __shared__ float Ks[KT][HD_];
  __shared__ float Vs[KT][HD_];

  const float scale = 0.17677669529663687f;  // 1/sqrt(32)
  float q[HD_];
  {
    const float* qptr = qkv + ((size_t)(b * S_ + qr)) * 768 + h * 32;
#pragma unroll
    for (int e = 0; e < HD_; e += 4) {
      float4 v4 = *(const float4*)(qptr + e);
      q[e + 0] = v4.x * scale; q[e + 1] = v4.y * scale;
      q[e + 2] = v4.z * scale; q[e + 3] = v4.w * scale;
    }
  }
  float mx = -1e30f, sum = 0.f;
  float acc[HD_] = {};

  const float* kbase = qkv + ((size_t)b * S_) * 768 + 256 + h * 32;
  const float* vbase = kbase + 256;
  const float* mrow  = cutoff + ((size_t)b * S_ + qr) * S_;

  for (int kt = 0; kt < S_; kt += KT) {
    __syncthreads();
    // stage K,V tiles: 64 rows x 32 floats each; 512 float4s per tile, 128 thr -> 4 iters
    for (int i = t; i < KT * 8; i += 128) {
      int r = i >> 3, c4 = (i & 7) * 4;
      *(float4*)&Ks[r][c4] = *(const float4*)(kbase + (size_t)(kt + r) * 768 + c4);
      *(float4*)&Vs[r][c4] = *(const float4*)(vbase + (size_t)(kt + r) * 768 + c4);
    }
    __syncthreads();

    for (int c = 0; c < KT; c += 16) {
      float s[16];
#pragma unroll
      for (int j = 0; j < 16; ++j) {
        const float* kr = &Ks[c + j][0];
        float d = 0.f;
#pragma unroll
        for (int e = 0; e < HD_; ++e) d = fmaf(q[e], kr[e], d);
        s[j] = d;
      }
#pragma unroll
      for (int j4 = 0; j4 < 16; j4 += 4) {
        float4 m4 = *(const float4*)(mrow + kt + c + j4);
        s[j4 + 0] += __logf(fmaxf(m4.x, 1e-15f));
        s[j4 + 1] += __logf(fmaxf(m4.y, 1e-15f));
        s[j4 + 2] += __logf(fmaxf(m4.z, 1e-15f));
        s[j4 + 3] += __logf(fmaxf(m4.w, 1e-15f));
      }
      float cmax = s[0];
#pragma unroll
      for (int j = 1; j < 16; ++j) cmax = fmaxf(cmax, s[j]);
      float nm = fmaxf(mx, cmax);
      float corr = __expf(mx - nm);
      sum *= corr;
#pragma unroll
      for (int e = 0; e < HD_; ++e) acc[e] *= corr;
#pragma unroll
      for (int j = 0; j < 16; ++j) {
        float p = __expf(s[j] - nm);
        sum += p;
        const float* vr = &Vs[c + j][0];
#pragma unroll
        for (int e = 0; e < HD_; ++e) acc[e] = fmaf(p, vr[e], acc[e]);
      }
      mx = nm;
    }
  }
  float inv = 1.f / sum;
  float* op = out + ((size_t)(b * S_ + qr)) * 256 + h * 32;
#pragma unroll
  for (int e = 0; e < HD_; e += 4) {
    float4 o4 = {acc[e] * inv, acc[e + 1] * inv, acc[e + 2] * inv, acc[e + 3] * inv};
    *(float4*)(op + e) = o4;
  }
}

// ---------------- fused residual + LayerNorm : out = LN(xa+xb)*g + b
// one wave per row (64 lanes x 4 floats = 256), block = 4 rows
__global__ __launch_bounds__(256) void residual_ln(const float* __restrict__ xa,
                                                   const float* __restrict__ xb,
                                                   const float* __restrict__ g,
                                                   const float* __restrict__ bt,
                                                   float* __restrict__ out) {
  const int row  = blockIdx.x * 4 + (threadIdx.x >> 6);
  const int lane = threadIdx.x & 63;
  float4 va = *(const float4*)(xa + (size_t)row * D_ + lane * 4);
  float4 vb = *(const float4*)(xb + (size_t)row * D_ + lane * 4);
  float v[4] = {va.x + vb.x, va.y + vb.y, va.z + vb.z, va.w + vb.w};
  float s = v[0] + v[1] + v[2] + v[3];
#pragma unroll
  for (int o = 32; o > 0; o >>= 1) s += __shfl_xor(s, o, 64);
  float mu = s * (1.f / D_);
  float var = 0.f;
#pragma unroll
  for (int i = 0; i < 4; ++i) { v[i] -= mu; var += v[i] * v[i]; }
#pragma unroll
  for (int o = 32; o > 0; o >>= 1) var += __shfl_xor(var, o, 64);
  float rs = rsqrtf(var * (1.f / D_) + 1e-5f);
  float4 g4 = *(const float4*)(g + lane * 4);
  float4 b4 = *(const float4*)(bt + lane * 4);
  float4 o4 = {v[0] * rs * g4.x + b4.x, v[1] * rs * g4.y + b4.y,
               v[2] * rs * g4.z + b4.z, v[3] * rs * g4.w + b4.w};
  *(float4*)(out + (size_t)row * D_ + lane * 4) = o4;
}

extern "C" void kernel_launch(void* const* d_in, const int* in_sizes, int n_in,
                              void* d_out, int out_size, void* d_ws, size_t ws_size,
                              hipStream_t stream) {
  const float* tokens = (const float*)d_in[0];
  const float* cutoff = (const float*)d_in[1];
  const float* Wqkv   = (const float*)d_in[2];
  const float* bqkv   = (const float*)d_in[3];
  const float* Wo     = (const float*)d_in[4];
  const float* bo     = (const float*)d_in[5];
  const float* ln1g   = (const float*)d_in[6];
  const float* ln1b   = (const float*)d_in[7];
  const float* ln2g   = (const float*)d_in[8];
  const float* ln2b   = (const float*)d_in[9];
  const float* W1     = (const float*)d_in[10];
  const float* b1     = (const float*)d_in[11];
  const float* W2     = (const float*)d_in[12];
  const float* b2     = (const float*)d_in[13];
  float* out = (float*)d_out;

  const size_t SZ = (size_t)B_ * S_ * D_;   // 2,097,152 floats = 8 MB
  float* ws      = (float*)d_ws;
  float* qkv     = ws;            // [0, 3SZ)   : live through attention
  float* attnOut = ws + 3 * SZ;   // [3SZ, 4SZ) : live through out-proj
  float* xbuf    = ws + 4 * SZ;   // [4SZ, 5SZ) : live to the end
  float* projOut = ws;            // reuse [0, SZ)      (qkv dead)
  float* hbuf    = ws + SZ;       // reuse [SZ, 3SZ)    (k,v dead)
  float* mlpOut  = ws + 3 * SZ;   // reuse attnOut

  const int M = B_ * S_;  // 8192

  // 1. QKV projection
  gemm_nt<0><<<dim3((3 * D_) / 64, M / 64), 256, 0, stream>>>(tokens, Wqkv, bqkv, qkv, M, 3 * D_, D_);
  // 2. attention
  attn_kernel<<<dim3((S_ / 128) * H_ * B_), 128, 0, stream>>>(qkv, cutoff, attnOut);
  // 3. output projection
  gemm_nt<0><<<dim3(D_ / 64, M / 64), 256, 0, stream>>>(attnOut, Wo, bo, projOut, M, D_, D_);
  // 4. residual + LN1
  residual_ln<<<dim3(M / 4), 256, 0, stream>>>(tokens, projOut, ln1g, ln1b, xbuf);
  // 5. MLP up + SiLU
  gemm_nt<1><<<dim3(DFF_ / 64, M / 64), 256, 0, stream>>>(xbuf, W1, b1, hbuf, M, DFF_, D_);
  // 6. MLP down
  gemm_nt<0><<<dim3(D_ / 64, M / 64), 256, 0, stream>>>(hbuf, W2, b2, mlpOut, M, D_, DFF_);
  // 7. residual + LN2 -> output
  residual_ln<<<dim3(M / 4), 256, 0, stream>>>(xbuf, mlpOut, ln2g, ln2b, out);
}

// Round 2
// 287.734 us; speedup vs baseline: 4.5302x; 4.5302x over previous
//
#include <hip/hip_runtime.h>
#include <hip/hip_bf16.h>
#include <math.h>

#define B_ 4
#define S_ 2048
#define D_ 256
#define H_ 8
#define HD_ 32
#define DFF_ 512

typedef __attribute__((ext_vector_type(8))) short bf16x8;
typedef __attribute__((ext_vector_type(4))) float f32x4;

__device__ inline short f2bf(float f) {
  union { float f; unsigned u; } x; x.f = f;
  unsigned r = (x.u + 0x7FFFu + ((x.u >> 16) & 1u)) >> 16;
  return (short)r;
}

// ---------------- generic NT GEMM: C[M,N] = A[M,K] * W[N,K]^T + bias, optional SiLU
template<int ACT>
__global__ __launch_bounds__(256) void gemm_nt(const float* __restrict__ A,
                                               const float* __restrict__ W,
                                               const float* __restrict__ bias,
                                               float* __restrict__ C,
                                               int M, int N, int K) {
  constexpr int BM = 64, BN = 64, BK = 16;
  __shared__ float As[BK][BM];
  __shared__ float Ws[BK][BN];
  const int tid = threadIdx.x;
  const int tx = tid & 15, ty = tid >> 4;
  const int rowBase = blockIdx.y * BM;
  const int colBase = blockIdx.x * BN;
  float acc[4][4] = {};
  for (int k0 = 0; k0 < K; k0 += BK) {
    __syncthreads();
    {
      int r  = tid >> 2;
      int k4 = (tid & 3) * 4;
      float4 v = *(const float4*)(A + (size_t)(rowBase + r) * K + k0 + k4);
      As[k4 + 0][r] = v.x; As[k4 + 1][r] = v.y; As[k4 + 2][r] = v.z; As[k4 + 3][r] = v.w;
      float4 wv = *(const float4*)(W + (size_t)(colBase + r) * K + k0 + k4);
      Ws[k4 + 0][r] = wv.x; Ws[k4 + 1][r] = wv.y; Ws[k4 + 2][r] = wv.z; Ws[k4 + 3][r] = wv.w;
    }
    __syncthreads();
#pragma unroll
    for (int kk = 0; kk < BK; ++kk) {
      float4 a4 = *(const float4*)&As[kk][ty * 4];
      float4 b4 = *(const float4*)&Ws[kk][tx * 4];
      float av[4] = {a4.x, a4.y, a4.z, a4.w};
      float bv[4] = {b4.x, b4.y, b4.z, b4.w};
#pragma unroll
      for (int i = 0; i < 4; ++i)
#pragma unroll
        for (int j = 0; j < 4; ++j)
          acc[i][j] = fmaf(av[i], bv[j], acc[i][j]);
    }
  }
#pragma unroll
  for (int i = 0; i < 4; ++i) {
    int row = rowBase + ty * 4 + i;
#pragma unroll
    for (int j = 0; j < 4; ++j) {
      int col = colBase + tx * 4 + j;
      float v = acc[i][j] + bias[col];
      if (ACT == 1) v = v / (1.f + __expf(-v));
      C[(size_t)row * N + col] = v;
    }
  }
}

// ---------------- MFMA flash attention (bf16 MFMA, f32 softmax state)
// grid: (S/128) * H * B blocks, 256 threads (4 waves, 32 q-rows each)
__global__ __launch_bounds__(256) void attn_mfma(const float* __restrict__ qkv,
                                                 const float* __restrict__ cutoff,
                                                 float* __restrict__ out) {
  constexpr int QB = 128, KB = 64;
  const int nqt = S_ / QB;            // 16
  const int qt = blockIdx.x % nqt;
  const int h  = (blockIdx.x / nqt) % H_;
  const int b  = blockIdx.x / (nqt * H_);
  const int tid = threadIdx.x;
  const int wid = tid >> 6;
  const int lane = tid & 63;
  const int g = lane >> 4;            // 0..3
  const int lc = lane & 15;

  // padded strides: 56/72 shorts -> 112/144 B rows, >=8 distinct banks for b128 reads
  __shared__ __align__(16) short Ks[KB][56];     // K row-major bf16
  __shared__ __align__(16) short Vt[HD_][72];    // V^T bf16
  __shared__ __align__(16) short Plds[4][32][72];// per-wave P

  const int qbase = qt * QB + wid * 32;
  const float scale = 0.17677669529663687f;  // 1/sqrt(32)

  // Q fragments (A-layout: row=lane&15, k=8*(lane>>4)+i), scale folded in
  bf16x8 qf[2];
#pragma unroll
  for (int m = 0; m < 2; ++m) {
    const float* qp = qkv + ((size_t)(b * S_ + qbase + m * 16 + lc)) * 768 + h * 32 + g * 8;
    float4 a = *(const float4*)qp;
    float4 c = *(const float4*)(qp + 4);
    bf16x8 t;
    t[0]=f2bf(a.x*scale); t[1]=f2bf(a.y*scale); t[2]=f2bf(a.z*scale); t[3]=f2bf(a.w*scale);
    t[4]=f2bf(c.x*scale); t[5]=f2bf(c.y*scale); t[6]=f2bf(c.z*scale); t[7]=f2bf(c.w*scale);
    qf[m] = t;
  }

  f32x4 oacc[2][2];   // [m][dfrag]
#pragma unroll
  for (int m=0;m<2;++m)
#pragma unroll
    for (int d=0;d<2;++d) { oacc[m][d][0]=0.f; oacc[m][d][1]=0.f; oacc[m][d][2]=0.f; oacc[m][d][3]=0.f; }
  float mx[2][4], sm[2][4];
#pragma unroll
  for (int m=0;m<2;++m)
#pragma unroll
    for (int r=0;r<4;++r){ mx[m][r]=-1e30f; sm[m][r]=0.f; }

  const float* kg = qkv + ((size_t)b * S_) * 768 + 256 + h * 32;
  const float* vg = kg + 256;
  // cutoff row base for this lane: q = qbase + g*4 + (m*16 + r), col offset lc
  const float* cb0 = cutoff + ((size_t)(b * S_) + qbase + g * 4) * (size_t)S_ + lc;

  for (int kt = 0; kt < S_; kt += KB) {
    __syncthreads();
    // stage K (row-major) and V^T, f32 -> bf16; 512 float4-tasks over 256 threads
    for (int it = tid; it < 512; it += 256) {
      int r = it >> 3, c4 = (it & 7) * 4;
      float4 kv = *(const float4*)(kg + (size_t)(kt + r) * 768 + c4);
      short4 s4; s4.x=f2bf(kv.x); s4.y=f2bf(kv.y); s4.z=f2bf(kv.z); s4.w=f2bf(kv.w);
      *(short4*)&Ks[r][c4] = s4;
      float4 vv = *(const float4*)(vg + (size_t)(kt + r) * 768 + c4);
      Vt[c4+0][r]=f2bf(vv.x); Vt[c4+1][r]=f2bf(vv.y);
      Vt[c4+2][r]=f2bf(vv.z); Vt[c4+3][r]=f2bf(vv.w);
    }
    __syncthreads();

    // QK^T: B-frag = K^T -> contiguous 8 d-elems of one K row
    bf16x8 kf[4];
#pragma unroll
    for (int n = 0; n < 4; ++n) kf[n] = *(const bf16x8*)&Ks[n*16 + lc][g*8];
    f32x4 sc[2][4];
#pragma unroll
    for (int m = 0; m < 2; ++m)
#pragma unroll
      for (int n = 0; n < 4; ++n) {
        f32x4 z = {0.f,0.f,0.f,0.f};
        sc[m][n] = __builtin_amdgcn_mfma_f32_16x16x32_bf16(qf[m], kf[n], z, 0, 0, 0);
      }

    // online softmax; probs = clamp(c,1e-15) * exp(s - m)   (log-mask algebraically removed)
#pragma unroll
    for (int m = 0; m < 2; ++m) {
      float nm[4], corr[4];
#pragma unroll
      for (int r = 0; r < 4; ++r) {
        float cm = fmaxf(fmaxf(sc[m][0][r], sc[m][1][r]), fmaxf(sc[m][2][r], sc[m][3][r]));
        cm = fmaxf(cm, __shfl_xor(cm, 1, 64));
        cm = fmaxf(cm, __shfl_xor(cm, 2, 64));
        cm = fmaxf(cm, __shfl_xor(cm, 4, 64));
        cm = fmaxf(cm, __shfl_xor(cm, 8, 64));
        float newm = fmaxf(mx[m][r], cm);
        corr[r] = __expf(mx[m][r] - newm);
        nm[r] = newm; mx[m][r] = newm;
      }
#pragma unroll
      for (int d = 0; d < 2; ++d)
#pragma unroll
        for (int r = 0; r < 4; ++r) oacc[m][d][r] *= corr[r];
      float rs[4] = {0.f,0.f,0.f,0.f};
#pragma unroll
      for (int n = 0; n < 4; ++n) {
#pragma unroll
        for (int r = 0; r < 4; ++r) {
          float cv = cb0[(size_t)(m*16 + r) * S_ + kt + n*16];
          cv = fmaxf(cv, 1e-15f);
          float p = cv * __expf(sc[m][n][r] - nm[r]);
          rs[r] += p;
          Plds[wid][m*16 + g*4 + r][n*16 + lc] = f2bf(p);
        }
      }
#pragma unroll
      for (int r = 0; r < 4; ++r) {
        float t = rs[r];
        t += __shfl_xor(t, 1, 64);
        t += __shfl_xor(t, 2, 64);
        t += __shfl_xor(t, 4, 64);
        t += __shfl_xor(t, 8, 64);
        sm[m][r] = sm[m][r] * corr[r] + t;
      }
    }

    // drain P writes (same-wave LDS RAW), then PV
    asm volatile("s_waitcnt lgkmcnt(0)" ::: "memory");

#pragma unroll
    for (int m = 0; m < 2; ++m)
#pragma unroll
      for (int kh = 0; kh < 2; ++kh) {
        bf16x8 pa = *(const bf16x8*)&Plds[wid][m*16 + lc][kh*32 + g*8];
#pragma unroll
        for (int d = 0; d < 2; ++d) {
          bf16x8 vb = *(const bf16x8*)&Vt[d*16 + lc][kh*32 + g*8];
          oacc[m][d] = __builtin_amdgcn_mfma_f32_16x16x32_bf16(pa, vb, oacc[m][d], 0, 0, 0);
        }
      }
  }

  // epilogue: normalize + store f32
#pragma unroll
  for (int m = 0; m < 2; ++m) {
#pragma unroll
    for (int r = 0; r < 4; ++r) {
      float inv = 1.f / sm[m][r];
      int q = qbase + m*16 + g*4 + r;
      float* op = out + ((size_t)(b * S_) + q) * D_ + h * 32 + lc;
      op[0]  = oacc[m][0][r] * inv;
      op[16] = oacc[m][1][r] * inv;
    }
  }
}

// ---------------- fused residual + LayerNorm
__global__ __launch_bounds__(256) void residual_ln(const float* __restrict__ xa,
                                                   const float* __restrict__ xb,
                                                   const float* __restrict__ g,
                                                   const float* __restrict__ bt,
                                                   float* __restrict__ out) {
  const int row  = blockIdx.x * 4 + (threadIdx.x >> 6);
  const int lane = threadIdx.x & 63;
  float4 va = *(const float4*)(xa + (size_t)row * D_ + lane * 4);
  float4 vb = *(const float4*)(xb + (size_t)row * D_ + lane * 4);
  float v[4] = {va.x + vb.x, va.y + vb.y, va.z + vb.z, va.w + vb.w};
  float s = v[0] + v[1] + v[2] + v[3];
#pragma unroll
  for (int o = 32; o > 0; o >>= 1) s += __shfl_xor(s, o, 64);
  float mu = s * (1.f / D_);
  float var = 0.f;
#pragma unroll
  for (int i = 0; i < 4; ++i) { v[i] -= mu; var += v[i] * v[i]; }
#pragma unroll
  for (int o = 32; o > 0; o >>= 1) var += __shfl_xor(var, o, 64);
  float rs = rsqrtf(var * (1.f / D_) + 1e-5f);
  float4 g4 = *(const float4*)(g + lane * 4);
  float4 b4 = *(const float4*)(bt + lane * 4);
  float4 o4 = {v[0] * rs * g4.x + b4.x, v[1] * rs * g4.y + b4.y,
               v[2] * rs * g4.z + b4.z, v[3] * rs * g4.w + b4.w};
  *(float4*)(out + (size_t)row * D_ + lane * 4) = o4;
}

extern "C" void kernel_launch(void* const* d_in, const int* in_sizes, int n_in,
                              void* d_out, int out_size, void* d_ws, size_t ws_size,
                              hipStream_t stream) {
  const float* tokens = (const float*)d_in[0];
  const float* cutoff = (const float*)d_in[1];
  const float* Wqkv   = (const float*)d_in[2];
  const float* bqkv   = (const float*)d_in[3];
  const float* Wo     = (const float*)d_in[4];
  const float* bo     = (const float*)d_in[5];
  const float* ln1g   = (const float*)d_in[6];
  const float* ln1b   = (const float*)d_in[7];
  const float* ln2g   = (const float*)d_in[8];
  const float* ln2b   = (const float*)d_in[9];
  const float* W1     = (const float*)d_in[10];
  const float* b1     = (const float*)d_in[11];
  const float* W2     = (const float*)d_in[12];
  const float* b2     = (const float*)d_in[13];
  float* out = (float*)d_out;

  const size_t SZ = (size_t)B_ * S_ * D_;
  float* ws      = (float*)d_ws;
  float* qkv     = ws;
  float* attnOut = ws + 3 * SZ;
  float* xbuf    = ws + 4 * SZ;
  float* projOut = ws;
  float* hbuf    = ws + SZ;
  float* mlpOut  = ws + 3 * SZ;

  const int M = B_ * S_;

  gemm_nt<0><<<dim3((3 * D_) / 64, M / 64), 256, 0, stream>>>(tokens, Wqkv, bqkv, qkv, M, 3 * D_, D_);
  attn_mfma<<<dim3((S_ / 128) * H_ * B_), 256, 0, stream>>>(qkv, cutoff, attnOut);
  gemm_nt<0><<<dim3(D_ / 64, M / 64), 256, 0, stream>>>(attnOut, Wo, bo, projOut, M, D_, D_);
  residual_ln<<<dim3(M / 4), 256, 0, stream>>>(tokens, projOut, ln1g, ln1b, xbuf);
  gemm_nt<1><<<dim3(DFF_ / 64, M / 64), 256, 0, stream>>>(xbuf, W1, b1, hbuf, M, DFF_, D_);
  gemm_nt<0><<<dim3(D_ / 64, M / 64), 256, 0, stream>>>(hbuf, W2, b2, mlpOut, M, D_, DFF_);
  residual_ln<<<dim3(M / 4), 256, 0, stream>>>(xbuf, mlpOut, ln2g, ln2b, out);
}

// Round 3
// 172.414 us; speedup vs baseline: 7.5602x; 1.6689x over previous
//
#include <hip/hip_runtime.h>
#include <hip/hip_bf16.h>
#include <math.h>

#define B_ 4
#define S_ 2048
#define D_ 256
#define H_ 8
#define HD_ 32
#define DFF_ 512

typedef __attribute__((ext_vector_type(8))) short bf16x8;
typedef __attribute__((ext_vector_type(4))) float f32x4;

__device__ inline short f2bf(float f) {
  union { float f; unsigned u; } x; x.f = f;
  unsigned r = (x.u + 0x7FFFu + ((x.u >> 16) & 1u)) >> 16;
  return (short)r;
}

// ---------------- f32 -> bf16 conversion (n multiple of 4)
__global__ __launch_bounds__(256) void cvt_f2bf(const float* __restrict__ src,
                                                short* __restrict__ dst, int n) {
  int i = (blockIdx.x * 256 + threadIdx.x) * 4;
  if (i < n) {
    float4 v = *(const float4*)(src + i);
    short4 s; s.x = f2bf(v.x); s.y = f2bf(v.y); s.z = f2bf(v.z); s.w = f2bf(v.w);
    *(short4*)(dst + i) = s;
  }
}

// ---------------- bf16 MFMA GEMM:  C[M,N] = A[M,K] * W[N,K]^T + bias
// MODE 0: f32 out (Cf) ; MODE 1: SiLU -> bf16 out (Cb) ; MODE 2: QKV scatter to [3][B,H,S,HD] bf16, Q scaled
template<int MODE>
__global__ __launch_bounds__(256) void gemm_bf(const short* __restrict__ A,
                                               const short* __restrict__ W,
                                               const float* __restrict__ bias,
                                               float* __restrict__ Cf,
                                               short* __restrict__ Cb,
                                               int M, int N, int K) {
  constexpr int BM = 128, BN = 64;
  __shared__ short As[BM][72];
  __shared__ short Bs[BN][72];
  const int tid = threadIdx.x;
  const int wid = tid >> 6, lane = tid & 63;
  const int g = lane >> 4, lc = lane & 15;
  const int wr = wid >> 1, wc = wid & 1;
  const int rowBase = blockIdx.y * BM;
  const int colBase = blockIdx.x * BN;

  f32x4 acc[4][2];
#pragma unroll
  for (int m = 0; m < 4; ++m)
#pragma unroll
    for (int n = 0; n < 2; ++n) { acc[m][n][0]=0.f; acc[m][n][1]=0.f; acc[m][n][2]=0.f; acc[m][n][3]=0.f; }

  for (int k0 = 0; k0 < K; k0 += 64) {
    __syncthreads();
#pragma unroll
    for (int i = 0; i < 4; ++i) {
      int task = tid + 256 * i;          // 1024 tasks: 128 rows x 8 chunks
      int r = task >> 3, c = (task & 7) * 8;
      *(bf16x8*)&As[r][c] = *(const bf16x8*)(A + (size_t)(rowBase + r) * K + k0 + c);
    }
#pragma unroll
    for (int i = 0; i < 2; ++i) {
      int task = tid + 256 * i;          // 512 tasks: 64 rows x 8 chunks
      int r = task >> 3, c = (task & 7) * 8;
      *(bf16x8*)&Bs[r][c] = *(const bf16x8*)(W + (size_t)(colBase + r) * K + k0 + c);
    }
    __syncthreads();
#pragma unroll
    for (int ks = 0; ks < 2; ++ks) {
      bf16x8 af[4], bfr[2];
#pragma unroll
      for (int m = 0; m < 4; ++m) af[m] = *(const bf16x8*)&As[wr*64 + m*16 + lc][ks*32 + g*8];
#pragma unroll
      for (int n = 0; n < 2; ++n) bfr[n] = *(const bf16x8*)&Bs[wc*32 + n*16 + lc][ks*32 + g*8];
#pragma unroll
      for (int m = 0; m < 4; ++m)
#pragma unroll
        for (int n = 0; n < 2; ++n)
          acc[m][n] = __builtin_amdgcn_mfma_f32_16x16x32_bf16(af[m], bfr[n], acc[m][n], 0, 0, 0);
    }
  }

#pragma unroll
  for (int m = 0; m < 4; ++m)
#pragma unroll
    for (int n = 0; n < 2; ++n) {
      int col = colBase + wc*32 + n*16 + lc;
      float bv = bias[col];
#pragma unroll
      for (int j = 0; j < 4; ++j) {
        int row = rowBase + wr*64 + m*16 + g*4 + j;
        float v = acc[m][n][j] + bv;
        if (MODE == 0) {
          Cf[(size_t)row * N + col] = v;
        } else if (MODE == 1) {
          v = v / (1.f + __expf(-v));
          Cb[(size_t)row * N + col] = f2bf(v);
        } else {  // QKV scatter
          int part = col >> 8;
          int h = (col >> 5) & 7;
          int hd = col & 31;
          int b = row >> 11, s = row & 2047;
          if (part == 0) v *= 0.17677669529663687f;   // 1/sqrt(32) folded into Q
          Cb[(size_t)part * 2097152 + ((((size_t)b * 8 + h) * 2048 + s) * 32 + hd)] = f2bf(v);
        }
      }
    }
}

// ---------------- MFMA flash attention, bf16 in / bf16 out
// grid: (S/128)*H*B = 512 blocks, 512 threads (8 waves, 16 q-rows each)
__global__ __launch_bounds__(512) void attn_mfma(const short* __restrict__ qkvbf,
                                                 const float* __restrict__ cutoff,
                                                 short* __restrict__ outbf) {
  constexpr int QB = 128, KB = 64;
  const int nqt = S_ / QB;            // 16
  const int qt = blockIdx.x % nqt;
  const int h  = (blockIdx.x / nqt) % H_;
  const int b  = blockIdx.x / (nqt * H_);
  const int tid = threadIdx.x;
  const int wid = tid >> 6;
  const int lane = tid & 63;
  const int g = lane >> 4, lc = lane & 15;

  __shared__ __align__(16) short Ks[KB][56];
  __shared__ __align__(16) short Vt[HD_][66];
  __shared__ __align__(16) short Plds[8][16][72];

  const int qbase = qt * QB + wid * 16;
  const size_t bh = ((size_t)b * H_ + h) * S_;
  const short* qg = qkvbf + bh * HD_;                 // part 0
  const short* kg = qkvbf + 2097152 + bh * HD_;       // part 1
  const short* vg = qkvbf + 2 * 2097152 + bh * HD_;   // part 2

  bf16x8 qf = *(const bf16x8*)(qg + (size_t)(qbase + lc) * HD_ + g * 8);

  f32x4 oacc[2];
#pragma unroll
  for (int d = 0; d < 2; ++d) { oacc[d][0]=0.f; oacc[d][1]=0.f; oacc[d][2]=0.f; oacc[d][3]=0.f; }
  float mx[4], sm[4];
#pragma unroll
  for (int r = 0; r < 4; ++r) { mx[r] = -1e30f; sm[r] = 0.f; }

  const float* cb = cutoff + ((size_t)(b * S_) + qbase + g * 4) * (size_t)S_ + lc;

  for (int kt = 0; kt < S_; kt += KB) {
    __syncthreads();
    if (tid < 256) {          // K: 64 rows x 4 chunks of 8 shorts
      int r = tid >> 2, c = (tid & 3) * 8;
      *(bf16x8*)&Ks[r][c] = *(const bf16x8*)(kg + (size_t)(kt + r) * HD_ + c);
    } else {                  // V^T: 64 rows x 4 chunks, scatter transpose
      int tv = tid - 256;
      int r = tv >> 2, c = (tv & 3) * 8;
      bf16x8 vv = *(const bf16x8*)(vg + (size_t)(kt + r) * HD_ + c);
#pragma unroll
      for (int j = 0; j < 8; ++j) Vt[c + j][r] = vv[j];
    }
    __syncthreads();

    // early cutoff loads (hide latency under MFMA)
    float cv[4][4];
#pragma unroll
    for (int n = 0; n < 4; ++n)
#pragma unroll
      for (int r = 0; r < 4; ++r)
        cv[n][r] = cb[(size_t)r * S_ + kt + n * 16];

    bf16x8 kf[4];
#pragma unroll
    for (int n = 0; n < 4; ++n) kf[n] = *(const bf16x8*)&Ks[n*16 + lc][g*8];
    f32x4 sc[4];
#pragma unroll
    for (int n = 0; n < 4; ++n) {
      f32x4 z = {0.f, 0.f, 0.f, 0.f};
      sc[n] = __builtin_amdgcn_mfma_f32_16x16x32_bf16(qf, kf[n], z, 0, 0, 0);
    }

    // online softmax: probs = clamp(c,1e-15) * exp(s - m); log-mask removed algebraically
    float nm[4], corr[4];
#pragma unroll
    for (int r = 0; r < 4; ++r) {
      float cm = fmaxf(fmaxf(sc[0][r], sc[1][r]), fmaxf(sc[2][r], sc[3][r]));
      cm = fmaxf(cm, __shfl_xor(cm, 1, 64));
      cm = fmaxf(cm, __shfl_xor(cm, 2, 64));
      cm = fmaxf(cm, __shfl_xor(cm, 4, 64));
      cm = fmaxf(cm, __shfl_xor(cm, 8, 64));
      nm[r] = fmaxf(mx[r], cm);
      corr[r] = __expf(mx[r] - nm[r]);
      mx[r] = nm[r];
    }
#pragma unroll
    for (int d = 0; d < 2; ++d)
#pragma unroll
      for (int r = 0; r < 4; ++r) oacc[d][r] *= corr[r];
    float rs[4] = {0.f, 0.f, 0.f, 0.f};
#pragma unroll
    for (int n = 0; n < 4; ++n)
#pragma unroll
      for (int r = 0; r < 4; ++r) {
        float p = fmaxf(cv[n][r], 1e-15f) * __expf(sc[n][r] - nm[r]);
        rs[r] += p;
        Plds[wid][g*4 + r][n*16 + lc] = f2bf(p);
      }
#pragma unroll
    for (int r = 0; r < 4; ++r) {
      float t = rs[r];
      t += __shfl_xor(t, 1, 64);
      t += __shfl_xor(t, 2, 64);
      t += __shfl_xor(t, 4, 64);
      t += __shfl_xor(t, 8, 64);
      sm[r] = sm[r] * corr[r] + t;
    }

    asm volatile("s_waitcnt lgkmcnt(0)" ::: "memory");
    __builtin_amdgcn_sched_barrier(0);

#pragma unroll
    for (int kh = 0; kh < 2; ++kh) {
      bf16x8 pa = *(const bf16x8*)&Plds[wid][lc][kh*32 + g*8];
#pragma unroll
      for (int d = 0; d < 2; ++d) {
        bf16x8 vb = *(const bf16x8*)&Vt[d*16 + lc][kh*32 + g*8];
        oacc[d] = __builtin_amdgcn_mfma_f32_16x16x32_bf16(pa, vb, oacc[d], 0, 0, 0);
      }
    }
  }

#pragma unroll
  for (int r = 0; r < 4; ++r) {
    float inv = 1.f / sm[r];
    int q = qbase + g*4 + r;
    short* op = outbf + ((size_t)(b * S_) + q) * D_ + h * HD_ + lc;
    op[0]  = f2bf(oacc[0][r] * inv);
    op[16] = f2bf(oacc[1][r] * inv);
  }
}

// ---------------- fused residual + LayerNorm (f32 out, optional bf16 copy)
template<int WBF>
__global__ __launch_bounds__(256) void residual_ln(const float* __restrict__ xa,
                                                   const float* __restrict__ xb,
                                                   const float* __restrict__ g,
                                                   const float* __restrict__ bt,
                                                   float* __restrict__ out,
                                                   short* __restrict__ outbf) {
  const int row  = blockIdx.x * 4 + (threadIdx.x >> 6);
  const int lane = threadIdx.x & 63;
  float4 va = *(const float4*)(xa + (size_t)row * D_ + lane * 4);
  float4 vb = *(const float4*)(xb + (size_t)row * D_ + lane * 4);
  float v[4] = {va.x + vb.x, va.y + vb.y, va.z + vb.z, va.w + vb.w};
  float s = v[0] + v[1] + v[2] + v[3];
#pragma unroll
  for (int o = 32; o > 0; o >>= 1) s += __shfl_xor(s, o, 64);
  float mu = s * (1.f / D_);
  float var = 0.f;
#pragma unroll
  for (int i = 0; i < 4; ++i) { v[i] -= mu; var += v[i] * v[i]; }
#pragma unroll
  for (int o = 32; o > 0; o >>= 1) var += __shfl_xor(var, o, 64);
  float rs = rsqrtf(var * (1.f / D_) + 1e-5f);
  float4 g4 = *(const float4*)(g + lane * 4);
  float4 b4 = *(const float4*)(bt + lane * 4);
  float4 o4 = {v[0] * rs * g4.x + b4.x, v[1] * rs * g4.y + b4.y,
               v[2] * rs * g4.z + b4.z, v[3] * rs * g4.w + b4.w};
  *(float4*)(out + (size_t)row * D_ + lane * 4) = o4;
  if (WBF) {
    short4 s4; s4.x = f2bf(o4.x); s4.y = f2bf(o4.y); s4.z = f2bf(o4.z); s4.w = f2bf(o4.w);
    *(short4*)(outbf + (size_t)row * D_ + lane * 4) = s4;
  }
}

extern "C" void kernel_launch(void* const* d_in, const int* in_sizes, int n_in,
                              void* d_out, int out_size, void* d_ws, size_t ws_size,
                              hipStream_t stream) {
  const float* tokens = (const float*)d_in[0];
  const float* cutoff = (const float*)d_in[1];
  const float* Wqkv   = (const float*)d_in[2];
  const float* bqkv   = (const float*)d_in[3];
  const float* Wo     = (const float*)d_in[4];
  const float* bo     = (const float*)d_in[5];
  const float* ln1g   = (const float*)d_in[6];
  const float* ln1b   = (const float*)d_in[7];
  const float* ln2g   = (const float*)d_in[8];
  const float* ln2b   = (const float*)d_in[9];
  const float* W1     = (const float*)d_in[10];
  const float* b1     = (const float*)d_in[11];
  const float* W2     = (const float*)d_in[12];
  const float* b2     = (const float*)d_in[13];
  float* out = (float*)d_out;

  char* w = (char*)d_ws;
  const size_t MB = 1 << 20;
  short* qkvbf  = (short*)w;                       // [0,12MB): q,k,v bf16 head-major
  short* tokbf  = (short*)(w + 12 * MB);           // [12,16MB)
  short* wq_bf  = (short*)(w + 16 * MB);           // 384KB
  short* wo_bf  = wq_bf + 196608;
  short* w1_bf  = wo_bf + 65536;
  short* w2_bf  = w1_bf + 131072;
  short* attnbf = tokbf;                           // reuse [12,16MB) after QKV GEMM
  float* projOut = (float*)(w + 18 * MB);          // [18,26MB)
  float* xbuf    = (float*)(w + 26 * MB);          // [26,34MB)
  short* xbbf    = qkvbf;                          // reuse [0,4MB) after attention
  short* hbbf    = qkvbf + 2097152;                // reuse [4,12MB)
  float* mlpOut  = projOut;                        // reuse after LN1

  const int M = B_ * S_;  // 8192

  // conversions
  cvt_f2bf<<<dim3(2048), 256, 0, stream>>>(tokens, tokbf, M * D_);
  cvt_f2bf<<<dim3(192),  256, 0, stream>>>(Wqkv, wq_bf, 3 * D_ * D_);
  cvt_f2bf<<<dim3(64),   256, 0, stream>>>(Wo,   wo_bf, D_ * D_);
  cvt_f2bf<<<dim3(128),  256, 0, stream>>>(W1,   w1_bf, DFF_ * D_);
  cvt_f2bf<<<dim3(128),  256, 0, stream>>>(W2,   w2_bf, D_ * DFF_);

  // 1. QKV projection -> bf16 head-major, Q pre-scaled
  gemm_bf<2><<<dim3(12, 64), 256, 0, stream>>>(tokbf, wq_bf, bqkv, nullptr, qkvbf, M, 3 * D_, D_);
  // 2. attention -> bf16 [M,256]
  attn_mfma<<<dim3(512), 512, 0, stream>>>(qkvbf, cutoff, attnbf);
  // 3. output projection -> f32
  gemm_bf<0><<<dim3(4, 64), 256, 0, stream>>>(attnbf, wo_bf, bo, projOut, nullptr, M, D_, D_);
  // 4. residual + LN1 -> f32 + bf16
  residual_ln<1><<<dim3(M / 4), 256, 0, stream>>>(tokens, projOut, ln1g, ln1b, xbuf, xbbf);
  // 5. MLP up + SiLU -> bf16
  gemm_bf<1><<<dim3(8, 64), 256, 0, stream>>>(xbbf, w1_bf, b1, nullptr, hbbf, M, DFF_, D_);
  // 6. MLP down -> f32
  gemm_bf<0><<<dim3(4, 64), 256, 0, stream>>>(hbbf, w2_bf, b2, mlpOut, nullptr, M, D_, DFF_);
  // 7. residual + LN2 -> output f32
  residual_ln<0><<<dim3(M / 4), 256, 0, stream>>>(xbuf, mlpOut, ln2g, ln2b, out, nullptr);
}

// Round 4
// 153.924 us; speedup vs baseline: 8.4684x; 1.1201x over previous
//
#include <hip/hip_runtime.h>
#include <hip/hip_bf16.h>
#include <math.h>

#define B_ 4
#define S_ 2048
#define D_ 256
#define H_ 8
#define HD_ 32
#define DFF_ 512

typedef __attribute__((ext_vector_type(8))) short bf16x8;
typedef __attribute__((ext_vector_type(4))) float f32x4;

__device__ inline short f2bf(float f) {
  union { float f; unsigned u; } x; x.f = f;
  unsigned r = (x.u + 0x7FFFu + ((x.u >> 16) & 1u)) >> 16;
  return (short)r;
}
__device__ inline float bf2f(short s) {
  union { unsigned u; float f; } x; x.u = ((unsigned)(unsigned short)s) << 16;
  return x.f;
}
__device__ inline unsigned cvt_pk_bf16(float a, float b) {
  unsigned r;
  asm("v_cvt_pk_bf16_f32 %0, %1, %2" : "=v"(r) : "v"(a), "v"(b));
  return r;
}

// ---------------- f32 -> bf16 conversion (n multiple of 4)
__global__ __launch_bounds__(256) void cvt_f2bf(const float* __restrict__ src,
                                                short* __restrict__ dst, int n) {
  int i = (blockIdx.x * 256 + threadIdx.x) * 4;
  if (i < n) {
    float4 v = *(const float4*)(src + i);
    short4 s; s.x = f2bf(v.x); s.y = f2bf(v.y); s.z = f2bf(v.z); s.w = f2bf(v.w);
    *(short4*)(dst + i) = s;
  }
}

// ---------------- bf16 MFMA GEMM:  C[M,N] = A[M,K] * W[N,K]^T + bias
// MODE 0: f32 out ; MODE 1: SiLU -> bf16 ; MODE 2: QKV scatter to [3][B,H,S,HD] bf16, Q scaled
template<int MODE>
__global__ __launch_bounds__(256) void gemm_bf(const short* __restrict__ A,
                                               const short* __restrict__ W,
                                               const float* __restrict__ bias,
                                               float* __restrict__ Cf,
                                               short* __restrict__ Cb,
                                               int M, int N, int K) {
  constexpr int BM = 128, BN = 64;
  __shared__ short As[BM][72];
  __shared__ short Bs[BN][72];
  const int tid = threadIdx.x;
  const int wid = tid >> 6, lane = tid & 63;
  const int g = lane >> 4, lc = lane & 15;
  const int wr = wid >> 1, wc = wid & 1;
  const int rowBase = blockIdx.y * BM;
  const int colBase = blockIdx.x * BN;

  f32x4 acc[4][2];
#pragma unroll
  for (int m = 0; m < 4; ++m)
#pragma unroll
    for (int n = 0; n < 2; ++n) { acc[m][n][0]=0.f; acc[m][n][1]=0.f; acc[m][n][2]=0.f; acc[m][n][3]=0.f; }

  for (int k0 = 0; k0 < K; k0 += 64) {
    __syncthreads();
#pragma unroll
    for (int i = 0; i < 4; ++i) {
      int task = tid + 256 * i;
      int r = task >> 3, c = (task & 7) * 8;
      *(bf16x8*)&As[r][c] = *(const bf16x8*)(A + (size_t)(rowBase + r) * K + k0 + c);
    }
#pragma unroll
    for (int i = 0; i < 2; ++i) {
      int task = tid + 256 * i;
      int r = task >> 3, c = (task & 7) * 8;
      *(bf16x8*)&Bs[r][c] = *(const bf16x8*)(W + (size_t)(colBase + r) * K + k0 + c);
    }
    __syncthreads();
#pragma unroll
    for (int ks = 0; ks < 2; ++ks) {
      bf16x8 af[4], bfr[2];
#pragma unroll
      for (int m = 0; m < 4; ++m) af[m] = *(const bf16x8*)&As[wr*64 + m*16 + lc][ks*32 + g*8];
#pragma unroll
      for (int n = 0; n < 2; ++n) bfr[n] = *(const bf16x8*)&Bs[wc*32 + n*16 + lc][ks*32 + g*8];
#pragma unroll
      for (int m = 0; m < 4; ++m)
#pragma unroll
        for (int n = 0; n < 2; ++n)
          acc[m][n] = __builtin_amdgcn_mfma_f32_16x16x32_bf16(af[m], bfr[n], acc[m][n], 0, 0, 0);
    }
  }

#pragma unroll
  for (int m = 0; m < 4; ++m)
#pragma unroll
    for (int n = 0; n < 2; ++n) {
      int col = colBase + wc*32 + n*16 + lc;
      float bv = bias[col];
#pragma unroll
      for (int j = 0; j < 4; ++j) {
        int row = rowBase + wr*64 + m*16 + g*4 + j;
        float v = acc[m][n][j] + bv;
        if (MODE == 0) {
          Cf[(size_t)row * N + col] = v;
        } else if (MODE == 1) {
          v = v / (1.f + __expf(-v));
          Cb[(size_t)row * N + col] = f2bf(v);
        } else {
          int part = col >> 8;
          int h = (col >> 5) & 7;
          int hd = col & 31;
          int b = row >> 11, s = row & 2047;
          if (part == 0) v *= 0.17677669529663687f;
          Cb[(size_t)part * 2097152 + ((((size_t)b * 8 + h) * 2048 + s) * 32 + hd)] = f2bf(v);
        }
      }
    }
}

// ---------------- per-(b,h): m_fixed[q] = |q_hat|2 * max_k |k_hat|2  (upper bound on all scores)
__global__ __launch_bounds__(256) void calc_mfix(const short* __restrict__ qkvbf,
                                                 float* __restrict__ mfix) {
  const int bh = blockIdx.x;          // 0..31
  const int t = threadIdx.x;
  const short* qg = qkvbf + (size_t)bh * S_ * HD_;
  const short* kg = qkvbf + 2097152 + (size_t)bh * S_ * HD_;
  __shared__ float red[256];
  float km2 = 0.f;
  for (int r = t; r < S_; r += 256) {
    const bf16x8* p = (const bf16x8*)(kg + (size_t)r * HD_);
    float ss = 0.f;
#pragma unroll
    for (int c = 0; c < 4; ++c) {
      bf16x8 v = p[c];
#pragma unroll
      for (int j = 0; j < 8; ++j) { float f = bf2f(v[j]); ss = fmaf(f, f, ss); }
    }
    km2 = fmaxf(km2, ss);
  }
  red[t] = km2;
  __syncthreads();
  for (int o = 128; o > 0; o >>= 1) {
    if (t < o) red[t] = fmaxf(red[t], red[t + o]);
    __syncthreads();
  }
  km2 = red[0];
  for (int r = t; r < S_; r += 256) {
    const bf16x8* p = (const bf16x8*)(qg + (size_t)r * HD_);
    float ss = 0.f;
#pragma unroll
    for (int c = 0; c < 4; ++c) {
      bf16x8 v = p[c];
#pragma unroll
      for (int j = 0; j < 8; ++j) { float f = bf2f(v[j]); ss = fmaf(f, f, ss); }
    }
    mfix[(size_t)bh * S_ + r] = sqrtf(ss * km2);
  }
}

// ---------------- MFMA flash attention, swapped-QK^T + fixed max
// grid: (S/128)*H*B = 512 blocks, 512 threads (8 waves, 16 q each)
__global__ __launch_bounds__(512) void attn_mfma(const short* __restrict__ qkvbf,
                                                 const float* __restrict__ cutoff,
                                                 const float* __restrict__ mfix,
                                                 short* __restrict__ outbf) {
  constexpr int KB = 64;
  const int nqt = S_ / 128;           // 16
  const int qt = blockIdx.x % nqt;
  const int h  = (blockIdx.x / nqt) % H_;
  const int b  = blockIdx.x / (nqt * H_);
  const int tid = threadIdx.x;
  const int wid = tid >> 6;
  const int lane = tid & 63;
  const int g = lane >> 4, lc = lane & 15;

  __shared__ __align__(16) short Ks[KB][56];     // K rows, 112B stride
  __shared__ __align__(16) short Vt[HD_][66];    // V^T, 132B stride (conflict-free scatter)
  __shared__ __align__(16) short Pq[8][16][72];  // per-wave P, q-major, 144B stride

  const int qrow = qt * 128 + wid * 16 + lc;     // this lane's q
  const size_t bh = ((size_t)b * H_ + h) * S_;
  const short* qg = qkvbf + bh * HD_;
  const short* kg = qkvbf + 2097152 + bh * HD_;
  const short* vg = qkvbf + 2 * 2097152 + bh * HD_;

  // Q as B-fragment: col = q = lc, k-elems = d = 8g+i
  bf16x8 qf = *(const bf16x8*)(qg + (size_t)qrow * HD_ + g * 8);
  const float m = mfix[bh + qrow];

  f32x4 oacc[2];
#pragma unroll
  for (int d = 0; d < 2; ++d) { oacc[d][0]=0.f; oacc[d][1]=0.f; oacc[d][2]=0.f; oacc[d][3]=0.f; }
  float sml = 0.f;

  const float* cb = cutoff + ((size_t)(b * S_) + qrow) * (size_t)S_;

  for (int kt = 0; kt < S_; kt += KB) {
    __syncthreads();
    if (tid < 256) {          // K: 64 rows x 4 chunks of 8 shorts
      int r = tid >> 2, c = (tid & 3) * 8;
      *(bf16x8*)&Ks[r][c] = *(const bf16x8*)(kg + (size_t)(kt + r) * HD_ + c);
    } else {                  // V^T scatter
      int tv = tid - 256;
      int r = tv >> 2, c = (tv & 3) * 8;
      bf16x8 vv = *(const bf16x8*)(vg + (size_t)(kt + r) * HD_ + c);
#pragma unroll
      for (int j = 0; j < 8; ++j) Vt[c + j][r] = vv[j];
    }
    __syncthreads();

    // cutoff: lane's 4 k's per tile are contiguous -> float4
    float4 cv[4];
#pragma unroll
    for (int t = 0; t < 4; ++t) cv[t] = *(const float4*)(cb + kt + t * 16 + g * 4);

    // S^T = mfma(K, Q): col = q = lc, row = k-local = 4g+j
    bf16x8 kf[4];
#pragma unroll
    for (int t = 0; t < 4; ++t) kf[t] = *(const bf16x8*)&Ks[t*16 + lc][g*8];
    f32x4 st[4];
#pragma unroll
    for (int t = 0; t < 4; ++t) {
      f32x4 z = {0.f, 0.f, 0.f, 0.f};
      st[t] = __builtin_amdgcn_mfma_f32_16x16x32_bf16(kf[t], qf, z, 0, 0, 0);
    }

    // p = clamp(c,1e-15) * exp(s - m_fixed): no online rescale needed (p <= 1 guaranteed)
#pragma unroll
    for (int t = 0; t < 4; ++t) {
      float p0 = fmaxf(cv[t].x, 1e-15f) * __expf(st[t][0] - m);
      float p1 = fmaxf(cv[t].y, 1e-15f) * __expf(st[t][1] - m);
      float p2 = fmaxf(cv[t].z, 1e-15f) * __expf(st[t][2] - m);
      float p3 = fmaxf(cv[t].w, 1e-15f) * __expf(st[t][3] - m);
      sml += (p0 + p1) + (p2 + p3);
      uint2 pk;
      pk.x = cvt_pk_bf16(p0, p1);
      pk.y = cvt_pk_bf16(p2, p3);
      *(uint2*)&Pq[wid][lc][t*16 + g*4] = pk;   // q-row-major, k-contiguous
    }

    asm volatile("s_waitcnt lgkmcnt(0)" ::: "memory");
    __builtin_amdgcn_sched_barrier(0);

    // O^T = mfma(V^T, P): A row = d-local, B col = q = lc
#pragma unroll
    for (int kh = 0; kh < 2; ++kh) {
      bf16x8 pb = *(const bf16x8*)&Pq[wid][lc][kh*32 + g*8];
#pragma unroll
      for (int dh = 0; dh < 2; ++dh) {
        bf16x8 va = *(const bf16x8*)&Vt[dh*16 + lc][kh*32 + g*8];
        oacc[dh] = __builtin_amdgcn_mfma_f32_16x16x32_bf16(va, pb, oacc[dh], 0, 0, 0);
      }
    }
  }

  // row-sum reduce across g-groups (lanes with same lc), once
  float s = sml;
  s += __shfl_xor(s, 16, 64);
  s += __shfl_xor(s, 32, 64);
  float inv = 1.f / s;

  // store: q = qrow, d = dh*16 + 4g + j (j contiguous)
#pragma unroll
  for (int dh = 0; dh < 2; ++dh) {
    uint2 pk;
    pk.x = cvt_pk_bf16(oacc[dh][0] * inv, oacc[dh][1] * inv);
    pk.y = cvt_pk_bf16(oacc[dh][2] * inv, oacc[dh][3] * inv);
    *(uint2*)(outbf + ((size_t)(b * S_) + qrow) * D_ + h * HD_ + dh * 16 + g * 4) = pk;
  }
}

// ---------------- fused residual + LayerNorm (f32 out, optional bf16 copy)
template<int WBF>
__global__ __launch_bounds__(256) void residual_ln(const float* __restrict__ xa,
                                                   const float* __restrict__ xb,
                                                   const float* __restrict__ g,
                                                   const float* __restrict__ bt,
                                                   float* __restrict__ out,
                                                   short* __restrict__ outbf) {
  const int row  = blockIdx.x * 4 + (threadIdx.x >> 6);
  const int lane = threadIdx.x & 63;
  float4 va = *(const float4*)(xa + (size_t)row * D_ + lane * 4);
  float4 vb = *(const float4*)(xb + (size_t)row * D_ + lane * 4);
  float v[4] = {va.x + vb.x, va.y + vb.y, va.z + vb.z, va.w + vb.w};
  float s = v[0] + v[1] + v[2] + v[3];
#pragma unroll
  for (int o = 32; o > 0; o >>= 1) s += __shfl_xor(s, o, 64);
  float mu = s * (1.f / D_);
  float var = 0.f;
#pragma unroll
  for (int i = 0; i < 4; ++i) { v[i] -= mu; var += v[i] * v[i]; }
#pragma unroll
  for (int o = 32; o > 0; o >>= 1) var += __shfl_xor(var, o, 64);
  float rs = rsqrtf(var * (1.f / D_) + 1e-5f);
  float4 g4 = *(const float4*)(g + lane * 4);
  float4 b4 = *(const float4*)(bt + lane * 4);
  float4 o4 = {v[0] * rs * g4.x + b4.x, v[1] * rs * g4.y + b4.y,
               v[2] * rs * g4.z + b4.z, v[3] * rs * g4.w + b4.w};
  *(float4*)(out + (size_t)row * D_ + lane * 4) = o4;
  if (WBF) {
    short4 s4; s4.x = f2bf(o4.x); s4.y = f2bf(o4.y); s4.z = f2bf(o4.z); s4.w = f2bf(o4.w);
    *(short4*)(outbf + (size_t)row * D_ + lane * 4) = s4;
  }
}

extern "C" void kernel_launch(void* const* d_in, const int* in_sizes, int n_in,
                              void* d_out, int out_size, void* d_ws, size_t ws_size,
                              hipStream_t stream) {
  const float* tokens = (const float*)d_in[0];
  const float* cutoff = (const float*)d_in[1];
  const float* Wqkv   = (const float*)d_in[2];
  const float* bqkv   = (const float*)d_in[3];
  const float* Wo     = (const float*)d_in[4];
  const float* bo     = (const float*)d_in[5];
  const float* ln1g   = (const float*)d_in[6];
  const float* ln1b   = (const float*)d_in[7];
  const float* ln2g   = (const float*)d_in[8];
  const float* ln2b   = (const float*)d_in[9];
  const float* W1     = (const float*)d_in[10];
  const float* b1     = (const float*)d_in[11];
  const float* W2     = (const float*)d_in[12];
  const float* b2     = (const float*)d_in[13];
  float* out = (float*)d_out;

  char* w = (char*)d_ws;
  const size_t MB = 1 << 20;
  short* qkvbf  = (short*)w;                       // [0,12MB)
  short* tokbf  = (short*)(w + 12 * MB);           // [12,16MB)
  short* wq_bf  = (short*)(w + 16 * MB);
  short* wo_bf  = wq_bf + 196608;
  short* w1_bf  = wo_bf + 65536;
  short* w2_bf  = w1_bf + 131072;
  short* attnbf = tokbf;                           // reuse after QKV GEMM
  float* projOut = (float*)(w + 18 * MB);          // [18,26MB)
  float* xbuf    = (float*)(w + 26 * MB);          // [26,34MB)
  float* mfix    = (float*)(w + 34 * MB);          // 256KB
  short* xbbf    = qkvbf;
  short* hbbf    = qkvbf + 2097152;
  float* mlpOut  = projOut;

  const int M = B_ * S_;

  cvt_f2bf<<<dim3(2048), 256, 0, stream>>>(tokens, tokbf, M * D_);
  cvt_f2bf<<<dim3(192),  256, 0, stream>>>(Wqkv, wq_bf, 3 * D_ * D_);
  cvt_f2bf<<<dim3(64),   256, 0, stream>>>(Wo,   wo_bf, D_ * D_);
  cvt_f2bf<<<dim3(128),  256, 0, stream>>>(W1,   w1_bf, DFF_ * D_);
  cvt_f2bf<<<dim3(128),  256, 0, stream>>>(W2,   w2_bf, D_ * DFF_);

  gemm_bf<2><<<dim3(12, 64), 256, 0, stream>>>(tokbf, wq_bf, bqkv, nullptr, qkvbf, M, 3 * D_, D_);
  calc_mfix<<<dim3(32), 256, 0, stream>>>(qkvbf, mfix);
  attn_mfma<<<dim3(512), 512, 0, stream>>>(qkvbf, cutoff, mfix, attnbf);
  gemm_bf<0><<<dim3(4, 64), 256, 0, stream>>>(attnbf, wo_bf, bo, projOut, nullptr, M, D_, D_);
  residual_ln<1><<<dim3(M / 4), 256, 0, stream>>>(tokens, projOut, ln1g, ln1b, xbuf, xbbf);
  gemm_bf<1><<<dim3(8, 64), 256, 0, stream>>>(xbbf, w1_bf, b1, nullptr, hbbf, M, DFF_, D_);
  gemm_bf<0><<<dim3(4, 64), 256, 0, stream>>>(hbbf, w2_bf, b2, mlpOut, nullptr, M, D_, DFF_);
  residual_ln<0><<<dim3(M / 4), 256, 0, stream>>>(xbuf, mlpOut, ln2g, ln2b, out, nullptr);
}

// Round 5
// 142.219 us; speedup vs baseline: 9.1654x; 1.0823x over previous
//
#include <hip/hip_runtime.h>
#include <hip/hip_bf16.h>
#include <math.h>

#define B_ 4
#define S_ 2048
#define D_ 256
#define H_ 8
#define HD_ 32
#define DFF_ 512

typedef __attribute__((ext_vector_type(8))) short bf16x8;
typedef __attribute__((ext_vector_type(4))) float f32x4;

__device__ inline short f2bf(float f) {
  union { float f; unsigned u; } x; x.f = f;
  unsigned r = (x.u + 0x7FFFu + ((x.u >> 16) & 1u)) >> 16;
  return (short)r;
}
__device__ inline float bf2f(short s) {
  union { unsigned u; float f; } x; x.u = ((unsigned)(unsigned short)s) << 16;
  return x.f;
}
__device__ inline unsigned cvt_pk_bf16(float a, float b) {
  unsigned r;
  asm("v_cvt_pk_bf16_f32 %0, %1, %2" : "=v"(r) : "v"(a), "v"(b));
  return r;
}
__device__ inline float exp2v(float x) {
  float r;
  asm("v_exp_f32 %0, %1" : "=v"(r) : "v"(x));
  return r;
}

// ---------------- merged f32->bf16 conversion: tokens + 4 weight matrices, one launch
__global__ __launch_bounds__(256) void cvt_all(const float* __restrict__ tok, const float* __restrict__ wq,
                                               const float* __restrict__ wo, const float* __restrict__ w1,
                                               const float* __restrict__ w2,
                                               short* __restrict__ dtok, short* __restrict__ dwq,
                                               short* __restrict__ dwo, short* __restrict__ dw1,
                                               short* __restrict__ dw2) {
  int blk = blockIdx.x;
  const float* src; short* dst; int base;
  if (blk < 2048)      { src = tok; dst = dtok; base = blk; }
  else if (blk < 2240) { src = wq;  dst = dwq;  base = blk - 2048; }
  else if (blk < 2304) { src = wo;  dst = dwo;  base = blk - 2240; }
  else if (blk < 2432) { src = w1;  dst = dw1;  base = blk - 2304; }
  else                 { src = w2;  dst = dw2;  base = blk - 2432; }
  int i = (base * 256 + threadIdx.x) * 4;
  float4 v = *(const float4*)(src + i);
  short4 s; s.x = f2bf(v.x); s.y = f2bf(v.y); s.z = f2bf(v.z); s.w = f2bf(v.w);
  *(short4*)(dst + i) = s;
}

// ---------------- bf16 MFMA GEMM, BM=128, BN=64:  C = A * W^T + bias
// MODE 1: SiLU -> bf16 ; MODE 2: QKV scatter (Q scaled by log2e/sqrt(32), V transposed [b,h,hd,s])
template<int MODE>
__global__ __launch_bounds__(256) void gemm_bf(const short* __restrict__ A,
                                               const short* __restrict__ W,
                                               const float* __restrict__ bias,
                                               float* __restrict__ Cf,
                                               short* __restrict__ Cb,
                                               int M, int N, int K) {
  constexpr int BM = 128, BN = 64;
  __shared__ short As[BM][72];
  __shared__ short Bs[BN][72];
  const int tid = threadIdx.x;
  const int wid = tid >> 6, lane = tid & 63;
  const int g = lane >> 4, lc = lane & 15;
  const int wr = wid >> 1, wc = wid & 1;
  const int rowBase = blockIdx.y * BM;
  const int colBase = blockIdx.x * BN;

  f32x4 acc[4][2];
#pragma unroll
  for (int m = 0; m < 4; ++m)
#pragma unroll
    for (int n = 0; n < 2; ++n) { acc[m][n][0]=0.f; acc[m][n][1]=0.f; acc[m][n][2]=0.f; acc[m][n][3]=0.f; }

  for (int k0 = 0; k0 < K; k0 += 64) {
    __syncthreads();
#pragma unroll
    for (int i = 0; i < 4; ++i) {
      int task = tid + 256 * i;
      int r = task >> 3, c = (task & 7) * 8;
      *(bf16x8*)&As[r][c] = *(const bf16x8*)(A + (size_t)(rowBase + r) * K + k0 + c);
    }
#pragma unroll
    for (int i = 0; i < 2; ++i) {
      int task = tid + 256 * i;
      int r = task >> 3, c = (task & 7) * 8;
      *(bf16x8*)&Bs[r][c] = *(const bf16x8*)(W + (size_t)(colBase + r) * K + k0 + c);
    }
    __syncthreads();
#pragma unroll
    for (int ks = 0; ks < 2; ++ks) {
      bf16x8 af[4], bfr[2];
#pragma unroll
      for (int m = 0; m < 4; ++m) af[m] = *(const bf16x8*)&As[wr*64 + m*16 + lc][ks*32 + g*8];
#pragma unroll
      for (int n = 0; n < 2; ++n) bfr[n] = *(const bf16x8*)&Bs[wc*32 + n*16 + lc][ks*32 + g*8];
#pragma unroll
      for (int m = 0; m < 4; ++m)
#pragma unroll
        for (int n = 0; n < 2; ++n)
          acc[m][n] = __builtin_amdgcn_mfma_f32_16x16x32_bf16(af[m], bfr[n], acc[m][n], 0, 0, 0);
    }
  }

#pragma unroll
  for (int m = 0; m < 4; ++m)
#pragma unroll
    for (int n = 0; n < 2; ++n) {
      int col = colBase + wc*32 + n*16 + lc;
      float bv = bias[col];
      int row0 = rowBase + wr*64 + m*16 + g*4;
      float vj[4];
#pragma unroll
      for (int j = 0; j < 4; ++j) vj[j] = acc[m][n][j] + bv;
      if (MODE == 1) {
#pragma unroll
        for (int j = 0; j < 4; ++j) {
          float v = vj[j];
          v = v / (1.f + __expf(-v));
          Cb[(size_t)(row0 + j) * N + col] = f2bf(v);
        }
      } else {  // MODE 2: QKV scatter
        int part = col >> 8;
        int h = (col >> 5) & 7;
        int hd = col & 31;
        int b = row0 >> 11, s0 = row0 & 2047;
        if (part == 2) {   // V transposed: [b,h,hd,s], s contiguous in j
          short4 s4;
          s4.x = f2bf(vj[0]); s4.y = f2bf(vj[1]); s4.z = f2bf(vj[2]); s4.w = f2bf(vj[3]);
          *(short4*)(Cb + 2 * 2097152 + (((size_t)b * 8 + h) * 32 + hd) * 2048 + s0) = s4;
        } else {
          float sc = (part == 0) ? 0.25506807f : 1.f;   // log2e / sqrt(32) folded into Q
#pragma unroll
          for (int j = 0; j < 4; ++j)
            Cb[(size_t)part * 2097152 + (((size_t)b * 8 + h) * 2048 + s0 + j) * 32 + hd] = f2bf(vj[j] * sc);
        }
      }
    }
}

// ---------------- bf16 MFMA GEMM, BM=64, BN=64 (f32 out) — for N=256 GEMMs (more blocks)
__global__ __launch_bounds__(256) void gemm_bf64(const short* __restrict__ A,
                                                 const short* __restrict__ W,
                                                 const float* __restrict__ bias,
                                                 float* __restrict__ Cf,
                                                 int M, int N, int K) {
  __shared__ short As[64][72];
  __shared__ short Bs[64][72];
  const int tid = threadIdx.x;
  const int wid = tid >> 6, lane = tid & 63;
  const int g = lane >> 4, lc = lane & 15;
  const int wr = wid >> 1, wc = wid & 1;
  const int rowBase = blockIdx.y * 64;
  const int colBase = blockIdx.x * 64;

  f32x4 acc[2][2];
#pragma unroll
  for (int m = 0; m < 2; ++m)
#pragma unroll
    for (int n = 0; n < 2; ++n) { acc[m][n][0]=0.f; acc[m][n][1]=0.f; acc[m][n][2]=0.f; acc[m][n][3]=0.f; }

  for (int k0 = 0; k0 < K; k0 += 64) {
    __syncthreads();
#pragma unroll
    for (int i = 0; i < 2; ++i) {
      int task = tid + 256 * i;
      int r = task >> 3, c = (task & 7) * 8;
      *(bf16x8*)&As[r][c] = *(const bf16x8*)(A + (size_t)(rowBase + r) * K + k0 + c);
      *(bf16x8*)&Bs[r][c] = *(const bf16x8*)(W + (size_t)(colBase + r) * K + k0 + c);
    }
    __syncthreads();
#pragma unroll
    for (int ks = 0; ks < 2; ++ks) {
      bf16x8 af[2], bfr[2];
#pragma unroll
      for (int m = 0; m < 2; ++m) af[m] = *(const bf16x8*)&As[wr*32 + m*16 + lc][ks*32 + g*8];
#pragma unroll
      for (int n = 0; n < 2; ++n) bfr[n] = *(const bf16x8*)&Bs[wc*32 + n*16 + lc][ks*32 + g*8];
#pragma unroll
      for (int m = 0; m < 2; ++m)
#pragma unroll
        for (int n = 0; n < 2; ++n)
          acc[m][n] = __builtin_amdgcn_mfma_f32_16x16x32_bf16(af[m], bfr[n], acc[m][n], 0, 0, 0);
    }
  }

#pragma unroll
  for (int m = 0; m < 2; ++m)
#pragma unroll
    for (int n = 0; n < 2; ++n) {
      int col = colBase + wc*32 + n*16 + lc;
      float bv = bias[col];
      int row0 = rowBase + wr*32 + m*16 + g*4;
#pragma unroll
      for (int j = 0; j < 4; ++j)
        Cf[(size_t)(row0 + j) * N + col] = acc[m][n][j] + bv;
    }
}

// ---------------- k-norm max per (b,h): kmax[bh] = max_k ||k||^2 (as u32-ordered float)
__global__ __launch_bounds__(256) void knorm_max(const short* __restrict__ kbf, unsigned* __restrict__ kmax) {
  const int bh = blockIdx.x >> 3;
  const int r = (blockIdx.x & 7) * 256 + threadIdx.x;
  const short* kp = kbf + ((size_t)bh * S_ + r) * HD_;
  float ss = 0.f;
#pragma unroll
  for (int c = 0; c < 4; ++c) {
    bf16x8 v = *(const bf16x8*)(kp + c * 8);
#pragma unroll
    for (int j = 0; j < 8; ++j) { float f = bf2f(v[j]); ss = fmaf(f, f, ss); }
  }
#pragma unroll
  for (int o = 1; o < 64; o <<= 1) ss = fmaxf(ss, __shfl_xor(ss, o, 64));
  __shared__ float red[4];
  if ((threadIdx.x & 63) == 0) red[threadIdx.x >> 6] = ss;
  __syncthreads();
  if (threadIdx.x == 0) {
    float mx = fmaxf(fmaxf(red[0], red[1]), fmaxf(red[2], red[3]));
    atomicMax(kmax + bh, __float_as_uint(mx));
  }
}

// ---------------- mfix[bh,q] = |q_hat| * max|k|  (upper bound on log2-scores, Cauchy-Schwarz)
__global__ __launch_bounds__(256) void q_mfix(const short* __restrict__ qbf,
                                              const unsigned* __restrict__ kmax,
                                              float* __restrict__ mfix) {
  const int bh = blockIdx.x >> 3;
  const int r = (blockIdx.x & 7) * 256 + threadIdx.x;
  const short* qp = qbf + ((size_t)bh * S_ + r) * HD_;
  float ss = 0.f;
#pragma unroll
  for (int c = 0; c < 4; ++c) {
    bf16x8 v = *(const bf16x8*)(qp + c * 8);
#pragma unroll
    for (int j = 0; j < 8; ++j) { float f = bf2f(v[j]); ss = fmaf(f, f, ss); }
  }
  mfix[(size_t)bh * S_ + r] = sqrtf(ss * __uint_as_float(kmax[bh]));
}

// ---------------- MFMA flash attention: QB=64, 4 waves, double-buffered reg-prefetch staging
// grid: 32 qt * 8 h * 4 b = 1024 blocks, 256 threads
__global__ __launch_bounds__(256, 4) void attn_mfma(const short* __restrict__ qbf,
                                                    const short* __restrict__ kbf,
                                                    const short* __restrict__ vtbf,
                                                    const float* __restrict__ cutoff,
                                                    const float* __restrict__ mfix,
                                                    short* __restrict__ outbf) {
  constexpr int KB = 64;
  const int qt = blockIdx.x & 31;
  const int h  = (blockIdx.x >> 5) & 7;
  const int b  = blockIdx.x >> 8;
  const int tid = threadIdx.x;
  const int wid = tid >> 6, lane = tid & 63;
  const int g = lane >> 4, lc = lane & 15;

  __shared__ __align__(16) short Ks[2][KB][56];    // K rows (k-major), 112B stride
  __shared__ __align__(16) short Vt[2][HD_][72];   // V^T rows (d-major), 144B stride
  __shared__ __align__(16) short Pq[4][16][72];    // per-wave P, q-major

  const int bh = b * H_ + h;
  const int qrow = qt * 64 + wid * 16 + lc;
  const short* qg = qbf + (size_t)bh * S_ * HD_;
  const short* kg = kbf + (size_t)bh * S_ * HD_;
  const short* vg = vtbf + (size_t)bh * HD_ * S_;

  bf16x8 qf = *(const bf16x8*)(qg + (size_t)qrow * HD_ + g * 8);
  const float m = mfix[(size_t)bh * S_ + qrow];

  f32x4 oacc[2];
#pragma unroll
  for (int d = 0; d < 2; ++d) { oacc[d][0]=0.f; oacc[d][1]=0.f; oacc[d][2]=0.f; oacc[d][3]=0.f; }
  float sml = 0.f;

  const float* cb = cutoff + ((size_t)(b * S_) + qrow) * (size_t)S_;

  // staging assignment (all 256 threads do one K-chunk and one V^T-chunk)
  const int kr = tid >> 2, kc = (tid & 3) * 8;   // K tile: 64 rows x 4 chunks
  const int vr = tid >> 3, vc = (tid & 7) * 8;   // V^T tile: 32 rows x 8 chunks
  const short* kptr = kg + (size_t)kr * HD_ + kc;
  const short* vptr = vg + (size_t)vr * S_ + vc;

  // prologue: tile 0
  bf16x8 kreg = *(const bf16x8*)kptr;
  bf16x8 vreg = *(const bf16x8*)vptr;
  *(bf16x8*)&Ks[0][kr][kc] = kreg;
  *(bf16x8*)&Vt[0][vr][vc] = vreg;
  float4 cv[4];
#pragma unroll
  for (int t = 0; t < 4; ++t) cv[t] = *(const float4*)(cb + t * 16 + g * 4);
  __syncthreads();

  int cur = 0;
#pragma unroll 2
  for (int kt = 0; kt < S_; kt += KB) {
    const bool notlast = (kt + KB < S_);
    if (notlast) {   // prefetch next K/V tile into regs (latency hidden under compute)
      kreg = *(const bf16x8*)(kptr + (size_t)(kt + KB) * HD_);
      vreg = *(const bf16x8*)(vptr + (kt + KB));
    }

    // S^T = mfma(K, Q): col = q = lc, row = k-local = 4g+j
    bf16x8 kf[4];
#pragma unroll
    for (int t = 0; t < 4; ++t) kf[t] = *(const bf16x8*)&Ks[cur][t*16 + lc][g*8];
    f32x4 st[4];
#pragma unroll
    for (int t = 0; t < 4; ++t) {
      f32x4 z = {0.f, 0.f, 0.f, 0.f};
      st[t] = __builtin_amdgcn_mfma_f32_16x16x32_bf16(kf[t], qf, z, 0, 0, 0);
    }

    float4 cvn[4];
    if (notlast) {   // prefetch next cutoff
#pragma unroll
      for (int t = 0; t < 4; ++t) cvn[t] = *(const float4*)(cb + kt + KB + t * 16 + g * 4);
    }

    // p = c * exp2(s - m_fixed)   (scores already in log2 units; p <= c <= 1)
#pragma unroll
    for (int t = 0; t < 4; ++t) {
      float p0 = cv[t].x * exp2v(st[t][0] - m);
      float p1 = cv[t].y * exp2v(st[t][1] - m);
      float p2 = cv[t].z * exp2v(st[t][2] - m);
      float p3 = cv[t].w * exp2v(st[t][3] - m);
      sml += (p0 + p1) + (p2 + p3);
      uint2 pk;
      pk.x = cvt_pk_bf16(p0, p1);
      pk.y = cvt_pk_bf16(p2, p3);
      *(uint2*)&Pq[wid][lc][t*16 + g*4] = pk;
    }

    asm volatile("s_waitcnt lgkmcnt(0)" ::: "memory");
    __builtin_amdgcn_sched_barrier(0);

    // O^T = mfma(V^T, P)
#pragma unroll
    for (int kh = 0; kh < 2; ++kh) {
      bf16x8 pb = *(const bf16x8*)&Pq[wid][lc][kh*32 + g*8];
#pragma unroll
      for (int dh = 0; dh < 2; ++dh) {
        bf16x8 va = *(const bf16x8*)&Vt[cur][dh*16 + lc][kh*32 + g*8];
        oacc[dh] = __builtin_amdgcn_mfma_f32_16x16x32_bf16(va, pb, oacc[dh], 0, 0, 0);
      }
    }

    if (notlast) {
      __syncthreads();                           // all waves done reading buf[cur^1]
      *(bf16x8*)&Ks[cur ^ 1][kr][kc] = kreg;     // write next tile
      *(bf16x8*)&Vt[cur ^ 1][vr][vc] = vreg;
      __syncthreads();                           // writes visible
      cur ^= 1;
#pragma unroll
      for (int t = 0; t < 4; ++t) cv[t] = cvn[t];
    }
  }

  // final row-sum reduce across g-groups, normalize, store
  float s = sml;
  s += __shfl_xor(s, 16, 64);
  s += __shfl_xor(s, 32, 64);
  float inv = 1.f / s;
#pragma unroll
  for (int dh = 0; dh < 2; ++dh) {
    uint2 pk;
    pk.x = cvt_pk_bf16(oacc[dh][0] * inv, oacc[dh][1] * inv);
    pk.y = cvt_pk_bf16(oacc[dh][2] * inv, oacc[dh][3] * inv);
    *(uint2*)(outbf + ((size_t)(b * S_) + qrow) * D_ + h * HD_ + dh * 16 + g * 4) = pk;
  }
}

// ---------------- fused residual + LayerNorm (f32 out, optional bf16 copy)
template<int WBF>
__global__ __launch_bounds__(256) void residual_ln(const float* __restrict__ xa,
                                                   const float* __restrict__ xb,
                                                   const float* __restrict__ g,
                                                   const float* __restrict__ bt,
                                                   float* __restrict__ out,
                                                   short* __restrict__ outbf) {
  const int row  = blockIdx.x * 4 + (threadIdx.x >> 6);
  const int lane = threadIdx.x & 63;
  float4 va = *(const float4*)(xa + (size_t)row * D_ + lane * 4);
  float4 vb = *(const float4*)(xb + (size_t)row * D_ + lane * 4);
  float v[4] = {va.x + vb.x, va.y + vb.y, va.z + vb.z, va.w + vb.w};
  float s = v[0] + v[1] + v[2] + v[3];
#pragma unroll
  for (int o = 32; o > 0; o >>= 1) s += __shfl_xor(s, o, 64);
  float mu = s * (1.f / D_);
  float var = 0.f;
#pragma unroll
  for (int i = 0; i < 4; ++i) { v[i] -= mu; var += v[i] * v[i]; }
#pragma unroll
  for (int o = 32; o > 0; o >>= 1) var += __shfl_xor(var, o, 64);
  float rs = rsqrtf(var * (1.f / D_) + 1e-5f);
  float4 g4 = *(const float4*)(g + lane * 4);
  float4 b4 = *(const float4*)(bt + lane * 4);
  float4 o4 = {v[0] * rs * g4.x + b4.x, v[1] * rs * g4.y + b4.y,
               v[2] * rs * g4.z + b4.z, v[3] * rs * g4.w + b4.w};
  *(float4*)(out + (size_t)row * D_ + lane * 4) = o4;
  if (WBF) {
    short4 s4; s4.x = f2bf(o4.x); s4.y = f2bf(o4.y); s4.z = f2bf(o4.z); s4.w = f2bf(o4.w);
    *(short4*)(outbf + (size_t)row * D_ + lane * 4) = s4;
  }
}

extern "C" void kernel_launch(void* const* d_in, const int* in_sizes, int n_in,
                              void* d_out, int out_size, void* d_ws, size_t ws_size,
                              hipStream_t stream) {
  const float* tokens = (const float*)d_in[0];
  const float* cutoff = (const float*)d_in[1];
  const float* Wqkv   = (const float*)d_in[2];
  const float* bqkv   = (const float*)d_in[3];
  const float* Wo     = (const float*)d_in[4];
  const float* bo     = (const float*)d_in[5];
  const float* ln1g   = (const float*)d_in[6];
  const float* ln1b   = (const float*)d_in[7];
  const float* ln2g   = (const float*)d_in[8];
  const float* ln2b   = (const float*)d_in[9];
  const float* W1     = (const float*)d_in[10];
  const float* b1     = (const float*)d_in[11];
  const float* W2     = (const float*)d_in[12];
  const float* b2     = (const float*)d_in[13];
  float* out = (float*)d_out;

  char* w = (char*)d_ws;
  const size_t MB = 1 << 20;
  short* qbf    = (short*)w;                       // [0,4MB)
  short* kbf    = qbf + 2097152;                   // [4,8MB)
  short* vtbf   = qbf + 2 * 2097152;               // [8,12MB)  V^T [b,h,hd,s]
  short* tokbf  = (short*)(w + 12 * MB);           // [12,16MB)
  short* wq_bf  = (short*)(w + 16 * MB);
  short* wo_bf  = wq_bf + 196608;
  short* w1_bf  = wo_bf + 65536;
  short* w2_bf  = w1_bf + 131072;
  short* attnbf = tokbf;                           // reuse after QKV GEMM
  float* projOut = (float*)(w + 18 * MB);          // [18,26MB)
  float* xbuf    = (float*)(w + 26 * MB);          // [26,34MB)
  float* mfix    = (float*)(w + 34 * MB);          // 256KB
  unsigned* kmax = (unsigned*)(w + 34 * MB + 262144);  // 128B
  short* xbbf    = qbf;                            // reuse after attention
  short* hbbf    = kbf;                            // reuse [4,12MB)
  float* mlpOut  = projOut;

  const int M = B_ * S_;

  cvt_all<<<dim3(2560), 256, 0, stream>>>(tokens, Wqkv, Wo, W1, W2, tokbf, wq_bf, wo_bf, w1_bf, w2_bf);
  hipMemsetAsync(kmax, 0, 128, stream);

  gemm_bf<2><<<dim3(12, 64), 256, 0, stream>>>(tokbf, wq_bf, bqkv, nullptr, qbf, M, 3 * D_, D_);
  knorm_max<<<dim3(256), 256, 0, stream>>>(kbf, kmax);
  q_mfix<<<dim3(256), 256, 0, stream>>>(qbf, kmax, mfix);
  attn_mfma<<<dim3(1024), 256, 0, stream>>>(qbf, kbf, vtbf, cutoff, mfix, attnbf);
  gemm_bf64<<<dim3(4, 128), 256, 0, stream>>>(attnbf, wo_bf, bo, projOut, M, D_, D_);
  residual_ln<1><<<dim3(M / 4), 256, 0, stream>>>(tokens, projOut, ln1g, ln1b, xbuf, xbbf);
  gemm_bf<1><<<dim3(8, 64), 256, 0, stream>>>(xbbf, w1_bf, b1, nullptr, hbbf, M, DFF_, D_);
  gemm_bf64<<<dim3(4, 128), 256, 0, stream>>>(hbbf, w2_bf, b2, mlpOut, M, D_, DFF_);
  residual_ln<0><<<dim3(M / 4), 256, 0, stream>>>(xbuf, mlpOut, ln2g, ln2b, out, nullptr);
}